// Round 4
// baseline (148.109 us; speedup 1.0000x reference)
//
#include <hip/hip_runtime.h>

// Locally-connected conv (BioConvolution): per-patch GEMM
//   Z[n,p,o] = sum_k X_patch[n,p,k] * F[p,k,o],  K=512, N=FOUT=32, P=1024
//   A = relu(Z + bias)
// One block per patch (grid=1024, fully resident at 4 blocks/CU).
// 256 threads = 4 waves; wave w computes the 16x16 tile (mi,ni).
// K processed in 2 halves of 256; X and F both staged per-half in bf16 LDS
// (33.8 KiB total -> 4 blocks/CU). Half-1 global loads are issued before the
// first barrier and kept in flight across the half-0 MFMA phase (raw
// s_barrier + lgkmcnt-only wait; never drain vmcnt mid-kernel).

typedef __attribute__((ext_vector_type(4))) float f32x4;
typedef __attribute__((ext_vector_type(4))) short s16x4;
typedef __attribute__((ext_vector_type(8))) short s16x8;

#define HWC (128 * 128 * 32)   // per-batch X stride (floats)
#define WC  (128 * 32)         // per-row X stride (floats)
#define FOUT 32
#define ROW 264                // 256 k + 8 pad shorts = 528 B row (16B aligned)

__device__ __forceinline__ short f2bf(float f) {
    // round-to-nearest-even fp32 -> bf16
    unsigned u = __builtin_bit_cast(unsigned, f);
    u += 0x7fffu + ((u >> 16) & 1u);
    return (short)(u >> 16);
}

__device__ __forceinline__ void barrier_lds_only() {
    // __syncthreads() would emit s_waitcnt vmcnt(0) and drain our prefetch.
    // LDS visibility only needs lgkmcnt(0) + barrier.
    asm volatile("s_waitcnt lgkmcnt(0)" ::: "memory");
    __builtin_amdgcn_s_barrier();
    asm volatile("" ::: "memory");
}

__launch_bounds__(256, 4)
__global__ void lcconv_kernel(const float* __restrict__ X,
                              const float* __restrict__ F,
                              const float* __restrict__ bias,
                              float* __restrict__ out) {
    __shared__ short Xs[32 * ROW];   // X half, bf16: [n][k_local]
    __shared__ short Fs[32 * ROW];   // F half, bf16 transposed: [o][k_local]

    const int p    = blockIdx.x;
    const int pr   = p >> 5;
    const int pc   = p & 31;
    const int tid  = threadIdx.x;
    const int lane = tid & 63;
    const int w    = tid >> 6;
    const int mi   = (w >> 1) * 16;
    const int ni   = (w & 1) * 16;

    const int xbase = pr * 4 * WC + pc * 128;   // (pr*4, pc*4, c=0)
    const float* Fp = F + p * (512 * FOUT);

    // ---- global-load issue for one K-half (16x dwordx4 per thread) ----
    auto loadX = [&](f32x4* xv, int h) {
        #pragma unroll
        for (int it = 0; it < 8; ++it) {
            int idx = it * 256 + tid;       // float4 id in [0,2048)
            int n   = idx >> 6;             // 64 float4 per n per half
            int il  = (idx >> 5) & 1;       // local patch row (i = 2h+il)
            int w4  = idx & 31;
            xv[it] = *(const f32x4*)(X + n * HWC + xbase + (2 * h + il) * WC + w4 * 4);
        }
    };
    auto loadF = [&](f32x4* fv, int h) {
        #pragma unroll
        for (int tt = 0; tt < 2; ++tt) {
            int task = tt * 256 + tid;      // [0,512)
            int o4   = task & 7;
            int k4   = task >> 3;           // [0,64)
            const float* fp0 = Fp + (h * 256 + k4 * 4) * FOUT + o4 * 4;
            #pragma unroll
            for (int d = 0; d < 4; ++d)
                fv[tt * 4 + d] = *(const f32x4*)(fp0 + d * FOUT);
        }
    };
    // ---- fp32 -> bf16 convert + LDS write for one K-half ----
    auto storeLDS = [&](const f32x4* xv, const f32x4* fv) {
        #pragma unroll
        for (int it = 0; it < 8; ++it) {
            int idx = it * 256 + tid;
            int n   = idx >> 6;
            int il  = (idx >> 5) & 1;
            int w4  = idx & 31;
            s16x4 b;
            b[0] = f2bf(xv[it][0]); b[1] = f2bf(xv[it][1]);
            b[2] = f2bf(xv[it][2]); b[3] = f2bf(xv[it][3]);
            *(s16x4*)(&Xs[n * ROW + il * 128 + w4 * 4]) = b;
        }
        #pragma unroll
        for (int tt = 0; tt < 2; ++tt) {
            int task = tt * 256 + tid;
            int o4   = task & 7;
            int k4   = task >> 3;
            #pragma unroll
            for (int e = 0; e < 4; ++e) {     // transpose 4x4 in registers
                s16x4 b;
                b[0] = f2bf(fv[tt * 4 + 0][e]); b[1] = f2bf(fv[tt * 4 + 1][e]);
                b[2] = f2bf(fv[tt * 4 + 2][e]); b[3] = f2bf(fv[tt * 4 + 3][e]);
                *(s16x4*)(&Fs[(o4 * 4 + e) * ROW + k4 * 4]) = b;
            }
        }
    };

    const int arow = mi + (lane & 15);
    const int brow = ni + (lane & 15);
    const int g16  = (lane >> 4) * 8;

    f32x4 acc = {0.f, 0.f, 0.f, 0.f};
    auto mfmaHalf = [&]() {
        #pragma unroll
        for (int ks = 0; ks < 8; ++ks) {
            // rows are 528 B (16B aligned) -> single ds_read_b128 per operand
            s16x8 a = *(const s16x8*)(&Xs[arow * ROW + ks * 32 + g16]);
            s16x8 b = *(const s16x8*)(&Fs[brow * ROW + ks * 32 + g16]);
            acc = __builtin_amdgcn_mfma_f32_16x16x32_bf16(a, b, acc, 0, 0, 0);
        }
    };

    f32x4 xa[8], fa[8], xb[8], fb[8];

    loadX(xa, 0);                 // 16 loads in flight (half 0)
    loadF(fa, 0);
    storeLDS(xa, fa);             // waits vmcnt incrementally, writes LDS
    loadX(xb, 1);                 // issue half-1 loads BEFORE the barrier;
    loadF(fb, 1);                 // they stay in flight through MFMA half 0
    barrier_lds_only();

    mfmaHalf();                   // half 0

    __builtin_amdgcn_s_barrier(); // reads of half-0 LDS are complete per-wave
    asm volatile("" ::: "memory");

    storeLDS(xb, fb);             // compiler inserts vmcnt waits for xb/fb here
    barrier_lds_only();

    mfmaHalf();                   // half 1

    // ---- epilogue: bias + ReLU, fp32 store ----
    // C/D layout: col = lane&15 (o), row = (lane>>4)*4 + reg (n)
    const int o_g = ni + (lane & 15);
    const float bv = bias[o_g];
    #pragma unroll
    for (int r = 0; r < 4; ++r) {
        int n_g = mi + (lane >> 4) * 4 + r;
        float v = acc[r] + bv;
        v = v > 0.f ? v : 0.f;
        out[n_g * (1024 * FOUT) + p * FOUT + o_g] = v;
    }
}

extern "C" void kernel_launch(void* const* d_in, const int* in_sizes, int n_in,
                              void* d_out, int out_size, void* d_ws, size_t ws_size,
                              hipStream_t stream) {
    const float* X    = (const float*)d_in[0];
    const float* F    = (const float*)d_in[1];
    const float* bias = (const float*)d_in[2];
    float* out        = (float*)d_out;
    lcconv_kernel<<<dim3(1024), dim3(256), 0, stream>>>(X, F, bias, out);
}

// Round 5
// 147.337 us; speedup vs baseline: 1.0052x; 1.0052x over previous
//
#include <hip/hip_runtime.h>

// Locally-connected conv (BioConvolution): per-patch GEMM
//   Z[n,p,o] = sum_k X_patch[n,p,k] * F[p,k,o],  K=512, N=FOUT=32, P=1024
//   A = relu(Z + bias)
// One block per patch, 512 threads = 8 waves. Full-K staged in ONE load burst
// (16x dwordx4 per thread, held in registers -> max MLP, single latency
// exposure). Waves (t,h): t = output 16x16 tile, h = K-half; cross-half
// reduce via 4KB LDS overlay. LDS = exactly 64 KiB (2 blocks/CU, 16 waves/CU)
// using a 16B-granular XOR swizzle instead of padding (bank-conflict-free
// b128 fragment reads).

typedef __attribute__((ext_vector_type(4))) float f32x4;
typedef __attribute__((ext_vector_type(4))) short s16x4;
typedef __attribute__((ext_vector_type(8))) short s16x8;

#define HWC (128 * 128 * 32)   // per-batch X stride (floats)
#define WC  (128 * 32)         // per-row X stride (floats)

__device__ __forceinline__ short f2bf(float f) {
    // round-to-nearest-even fp32 -> bf16
    unsigned u = __builtin_bit_cast(unsigned, f);
    u += 0x7fffu + ((u >> 16) & 1u);
    return (short)(u >> 16);
}

// Swizzled short-index into a [row][512] bf16 tile: XOR bytes 16/32/64 with
// row&7 -> rows 0..7 hit distinct bank-quads; 16B chunks stay contiguous
// (XOR value is a multiple of 8 shorts), so b64 writes / b128 reads are legal.
__device__ __forceinline__ int swz(int row, int k) {
    return row * 512 + (k ^ ((row & 7) << 3));
}

__launch_bounds__(512, 4)
__global__ void lcconv_kernel(const float* __restrict__ X,
                              const float* __restrict__ F,
                              const float* __restrict__ bias,
                              float* __restrict__ out) {
    __shared__ short Xs[32 * 512];   // [n][k] bf16, swizzled   (32 KiB)
    __shared__ short Fs[32 * 512];   // [o][k] bf16, swizzled   (32 KiB)

    const int p    = blockIdx.x;
    const int pr   = p >> 5;
    const int pc   = p & 31;
    const int tid  = threadIdx.x;    // 0..511
    const int lane = tid & 63;
    const int w    = tid >> 6;       // 0..7
    const int t    = w & 3;          // output tile id
    const int h    = w >> 2;         // K half (0: k<256, 1: k>=256)
    const int mi   = (t >> 1) * 16;
    const int ni   = (t & 1) * 16;

    // ------------- issue ALL global loads in one burst (16/thread) --------
    f32x4 xv[8], fv[8];
    {
        const int xbase = pr * 4 * WC + pc * 128;   // (pr*4, pc*4, c=0)
        #pragma unroll
        for (int it = 0; it < 8; ++it) {
            int idx = it * 512 + tid;      // f32x4 id in [0,4096)
            int n   = idx >> 7;            // 128 f32x4 per n
            int r   = idx & 127;
            int i   = r >> 5;              // patch row 0..3
            int w4  = r & 31;
            xv[it] = *(const f32x4*)(X + n * HWC + xbase + i * WC + w4 * 4);
        }
        const float* Fp = F + p * (512 * 32);
        #pragma unroll
        for (int tt = 0; tt < 2; ++tt) {
            int task = tt * 512 + tid;     // [0,1024)
            int o4   = task & 7;
            int k4   = task >> 3;          // [0,128)
            const float* fp0 = Fp + k4 * 4 * 32 + o4 * 4;
            #pragma unroll
            for (int d = 0; d < 4; ++d)
                fv[tt * 4 + d] = *(const f32x4*)(fp0 + d * 32);
        }
    }
    // Pin all load issues above; conversions below wait vmcnt incrementally.
    asm volatile("" ::: "memory");

    // ------------- convert fp32 -> bf16, write LDS -------------------------
    {
        #pragma unroll
        for (int it = 0; it < 8; ++it) {
            int idx = it * 512 + tid;
            int n   = idx >> 7;
            int r   = idx & 127;
            int i   = r >> 5;
            int w4  = r & 31;
            s16x4 b;
            b[0] = f2bf(xv[it][0]); b[1] = f2bf(xv[it][1]);
            b[2] = f2bf(xv[it][2]); b[3] = f2bf(xv[it][3]);
            *(s16x4*)(&Xs[swz(n, i * 128 + w4 * 4)]) = b;
        }
        #pragma unroll
        for (int tt = 0; tt < 2; ++tt) {
            int task = tt * 512 + tid;
            int o4   = task & 7;
            int k4   = task >> 3;
            #pragma unroll
            for (int e = 0; e < 4; ++e) {   // 4x4 register transpose
                s16x4 b;
                b[0] = f2bf(fv[tt * 4 + 0][e]); b[1] = f2bf(fv[tt * 4 + 1][e]);
                b[2] = f2bf(fv[tt * 4 + 2][e]); b[3] = f2bf(fv[tt * 4 + 3][e]);
                *(s16x4*)(&Fs[swz(o4 * 4 + e, k4 * 4)]) = b;
            }
        }
    }
    __syncthreads();

    // ------------- MFMA: this wave's (tile t, K-half h) --------------------
    f32x4 acc = {0.f, 0.f, 0.f, 0.f};
    {
        const int arow = mi + (lane & 15);
        const int brow = ni + (lane & 15);
        const int g16  = (lane >> 4) * 8;
        const int kb   = h * 256;
        #pragma unroll
        for (int ks = 0; ks < 8; ++ks) {
            s16x8 a = *(const s16x8*)(&Xs[swz(arow, kb + ks * 32 + g16)]);
            s16x8 b = *(const s16x8*)(&Fs[swz(brow, kb + ks * 32 + g16)]);
            acc = __builtin_amdgcn_mfma_f32_16x16x32_bf16(a, b, acc, 0, 0, 0);
        }
    }
    __syncthreads();   // all Xs/Fs reads done -> safe to overlay rbuf

    // ------------- cross-half reduce (overlay on Xs), epilogue -------------
    float* rbuf = (float*)Xs;          // 4 tiles * 4 regs * 64 lanes = 4 KiB
    if (h == 1) {
        #pragma unroll
        for (int r = 0; r < 4; ++r)
            rbuf[(t * 4 + r) * 64 + lane] = acc[r];
    }
    __syncthreads();
    if (h == 0) {
        // C/D layout: col o = lane&15, row n = (lane>>4)*4 + reg
        const int o_g = ni + (lane & 15);
        const float bv = bias[o_g];
        #pragma unroll
        for (int r = 0; r < 4; ++r) {
            int n_g = mi + (lane >> 4) * 4 + r;
            float v = acc[r] + rbuf[(t * 4 + r) * 64 + lane] + bv;
            v = v > 0.f ? v : 0.f;
            out[n_g * (1024 * 32) + p * 32 + o_g] = v;
        }
    }
}

extern "C" void kernel_launch(void* const* d_in, const int* in_sizes, int n_in,
                              void* d_out, int out_size, void* d_ws, size_t ws_size,
                              hipStream_t stream) {
    const float* X    = (const float*)d_in[0];
    const float* F    = (const float*)d_in[1];
    const float* bias = (const float*)d_in[2];
    float* out        = (float*)d_out;
    lcconv_kernel<<<dim3(1024), dim3(512), 0, stream>>>(X, F, bias, out);
}